// Round 7
// baseline (554.771 us; speedup 1.0000x reference)
//
#include <hip/hip_runtime.h>
#include <hip/hip_bf16.h>

#define T_SEQ 2048
#define HIDDEN_SZ 4096
#define NUM_HEADS 32
#define HEAD_DIM 128
#define KV_GROUPS 2
#define Q_SZ 4096          // NUM_HEADS*HEAD_DIM
#define KV_SZ 256          // KV_GROUPS*HEAD_DIM
#define QKV_DIM 4608       // Q_SZ + 2*KV_SZ

typedef __attribute__((ext_vector_type(8))) short bf16x8_t;   // 8 bf16 = 4 VGPR (A/B frag)
typedef __attribute__((ext_vector_type(4))) float f32x4_t;    // C/D frag

__device__ inline void store_c(float* p, float v) { *p = v; }
__device__ inline void store_c(__hip_bfloat16* p, float v) { *p = __float2bfloat16(v); }

// async global->LDS, 16B per lane; LDS dest = wave-uniform base + lane*16
#define GLDS16(gp, lp)                                                                  \
    __builtin_amdgcn_global_load_lds((const __attribute__((address_space(1))) unsigned int*)(gp), \
                                     (__attribute__((address_space(3))) unsigned int*)(lp), 16, 0, 0)

// ---------------- fp32 -> bf16 contiguous convert ----------------
__global__ __launch_bounds__(256) void convert_bf16_kernel(const float* __restrict__ in,
                                                           __hip_bfloat16* __restrict__ out,
                                                           int n) {
    int i = (blockIdx.x * 256 + threadIdx.x) * 4;
    if (i + 3 < n) {
        float4 v = *reinterpret_cast<const float4*>(in + i);
        alignas(8) __hip_bfloat16 tmp[4] = {__float2bfloat16(v.x), __float2bfloat16(v.y),
                                            __float2bfloat16(v.z), __float2bfloat16(v.w)};
        *reinterpret_cast<ushort4*>(out + i) = *reinterpret_cast<const ushort4*>(tmp);
    }
}

// ---------------- fp32 [R][C] -> bf16 [C][R] tile transpose (64x64, vectorized) ----------------
__global__ __launch_bounds__(256) void transpose_convert_kernel(const float* __restrict__ in,
                                                                __hip_bfloat16* __restrict__ out,
                                                                int R, int C) {
    __shared__ float tile[64][65];   // pad 65: column reads conflict-free
    const int tx = threadIdx.x & 15;   // 0..15
    const int ty = threadIdx.x >> 4;   // 0..15
    const int c0 = blockIdx.x * 64, r0 = blockIdx.y * 64;
    #pragma unroll
    for (int i = 0; i < 4; ++i) {
        int row = ty + 16 * i;
        float4 v = *reinterpret_cast<const float4*>(&in[(size_t)(r0 + row) * C + c0 + tx * 4]);
        tile[row][tx * 4 + 0] = v.x; tile[row][tx * 4 + 1] = v.y;
        tile[row][tx * 4 + 2] = v.z; tile[row][tx * 4 + 3] = v.w;
    }
    __syncthreads();
    #pragma unroll
    for (int i = 0; i < 4; ++i) {
        int ocol = ty + 16 * i;
        alignas(8) __hip_bfloat16 o[4];
        #pragma unroll
        for (int j = 0; j < 4; ++j) o[j] = __float2bfloat16(tile[tx * 4 + j][ocol]);
        *reinterpret_cast<ushort4*>(&out[(size_t)(c0 + ocol) * R + r0 + tx * 4]) =
            *reinterpret_cast<const ushort4*>(o);
    }
}

// ---------------- bf16 MFMA GEMM: C[M][N] = A[M][K] * BT[N][K]^T (+bias) ----------------
// Phase-split schedule (round 6, resubmitted round 7 after container-level failure —
// audit found no hang/fault mechanism; rounds 4/5 already exercised counted-vmcnt +
// raw s_barrier + 3-buffer rotation successfully):
//   - BM=128 x BN=256, BK=32, 8 waves (512 thr), wave tile 64x64 (fragment math
//     identical to the verified 4-wave kernel).
//   - 3 LDS buffers (72 KB), prefetch distance 2, COUNTED s_waitcnt vmcnt(4):
//     newer-than-t loads in flight = t+1's 3 + t+2's A 1 = 4. Tail: vmcnt(3) at
//     t=NT-2, vmcnt(0) only at the last tile.
//   - 2 phases per K-tile: {stage-issue || ds_read || 8 MFMA} each, with
//     lgkmcnt(0)+sched_barrier(0) (rule-18) and s_setprio(1) around MFMA (T5).
//   - T2 LDS XOR swizzle, both-sides-or-neither (rule-21): GLDS dest LINEAR; global
//     source col pre-swizzled by s(row)=((row>>1)&3); ds_read applies the same XOR.
//     Fragment read conflicts drop from 8-way to 2-way (free).
// Buffer safety: buf (t+2)%3 == (t-1)%3 is freed by the end-of-tile-(t-1) barrier,
// which precedes tile t's stage issues in program order.
template <typename OutT>
__global__ __launch_bounds__(512) void gemm_bf16_kernel(const __hip_bfloat16* __restrict__ A,
                                                        const __hip_bfloat16* __restrict__ BT,
                                                        const float* __restrict__ bias,
                                                        OutT* __restrict__ C,
                                                        int M, int N, int K) {
    constexpr int BM = 128, BN = 256, BK = 32;
    __shared__ __hip_bfloat16 lA[3][BM * BK];   // 3 x 8 KB
    __shared__ __hip_bfloat16 lB[3][BN * BK];   // 3 x 16 KB
    const int tid = threadIdx.x;
    // XCD swizzle: work id = (bid%8)*(nwg/8) + bid/8  (bijective when nwg%8==0)
    const int nwg = gridDim.x * gridDim.y;
    const int bid = blockIdx.y * gridDim.x + blockIdx.x;
    const int swz = (bid & 7) * (nwg >> 3) + (bid >> 3);
    const int bm = (swz / gridDim.x) * BM, bn = (swz % gridDim.x) * BN;
    const int wave = tid >> 6, lane = tid & 63;
    const int wr = wave >> 2, wc = wave & 3;          // 2 x 4 wave grid, wave tile 64x64
    const int n16 = lane & 15, quad = lane >> 4;
    const int c16s = (n16 >> 1) & 3;                  // read-side swizzle term
    const int gsw = (lane & 3) ^ ((lane >> 3) & 3);   // staging source pre-swizzle
    f32x4_t acc[4][4] = {};

    // stage tile t: A = 1 GLDS/thread (128 rows), B = 2 GLDS/thread (256 rows).
    // LDS dest linear (wave covers 16 rows = 1 KB); global source col16 = gsw.
    auto STAGE_A = [&](int buf, int t) {
        const int kk = t * BK;
        const int row = wave * 16 + (lane >> 2);
        GLDS16(&A[(size_t)(bm + row) * K + kk + gsw * 8], &lA[buf][wave * 512]);
    };
    auto STAGE_B = [&](int buf, int t) {
        const int kk = t * BK;
        #pragma unroll
        for (int r2 = 0; r2 < 2; ++r2) {
            const int row = r2 * 128 + wave * 16 + (lane >> 2);
            GLDS16(&BT[(size_t)(bn + row) * K + kk + gsw * 8],
                   &lB[buf][(r2 * 128 + wave * 16) * 32]);
        }
    };
    auto LDA = [&](int buf, int i) {
        return *reinterpret_cast<const bf16x8_t*>(
            &lA[buf][(wr * 64 + i * 16 + n16) * 32 + ((quad ^ c16s) << 3)]);
    };
    auto LDB = [&](int buf, int j) {
        return *reinterpret_cast<const bf16x8_t*>(
            &lB[buf][(wc * 64 + j * 16 + n16) * 32 + ((quad ^ c16s) << 3)]);
    };

    const int NT = K / BK;                          // 128
    STAGE_A(0, 0); STAGE_B(0, 0);                   // prologue: tiles 0,1 in flight (6 loads)
    STAGE_A(1, 1); STAGE_B(1, 1);
    int bufc = 0;
    for (int t = 0; t < NT; ++t) {
        int bufn = bufc + 2; if (bufn >= 3) bufn -= 3;
        // ---- phase 0 ----
        if (t + 2 < NT) STAGE_A(bufn, t + 2);
        if (t < NT - 2)      asm volatile("s_waitcnt vmcnt(4)" ::: "memory");
        else if (t < NT - 1) asm volatile("s_waitcnt vmcnt(3)" ::: "memory");
        else                 asm volatile("s_waitcnt vmcnt(0)" ::: "memory");
        __builtin_amdgcn_s_barrier();               // tile t resident (all waves vmcnt'd)
        __builtin_amdgcn_sched_barrier(0);
        bf16x8_t af[4], bfr[4];
        #pragma unroll
        for (int i = 0; i < 4; ++i) af[i] = LDA(bufc, i);
        bfr[0] = LDB(bufc, 0); bfr[1] = LDB(bufc, 1);
        asm volatile("s_waitcnt lgkmcnt(0)" ::: "memory");
        __builtin_amdgcn_sched_barrier(0);
        __builtin_amdgcn_s_setprio(1);
        #pragma unroll
        for (int i = 0; i < 4; ++i) {
            acc[i][0] = __builtin_amdgcn_mfma_f32_16x16x32_bf16(af[i], bfr[0], acc[i][0], 0, 0, 0);
            acc[i][1] = __builtin_amdgcn_mfma_f32_16x16x32_bf16(af[i], bfr[1], acc[i][1], 0, 0, 0);
        }
        __builtin_amdgcn_s_setprio(0);
        // ---- phase 1 ----
        if (t + 2 < NT) STAGE_B(bufn, t + 2);
        bfr[2] = LDB(bufc, 2); bfr[3] = LDB(bufc, 3);
        asm volatile("s_waitcnt lgkmcnt(0)" ::: "memory");
        __builtin_amdgcn_sched_barrier(0);
        __builtin_amdgcn_s_setprio(1);
        #pragma unroll
        for (int i = 0; i < 4; ++i) {
            acc[i][2] = __builtin_amdgcn_mfma_f32_16x16x32_bf16(af[i], bfr[2], acc[i][2], 0, 0, 0);
            acc[i][3] = __builtin_amdgcn_mfma_f32_16x16x32_bf16(af[i], bfr[3], acc[i][3], 0, 0, 0);
        }
        __builtin_amdgcn_s_setprio(0);
        __builtin_amdgcn_s_barrier();               // all waves done with buf bufc
        bufc = bufc + 1; if (bufc >= 3) bufc -= 3;
    }

    #pragma unroll
    for (int i = 0; i < 4; ++i) {
        #pragma unroll
        for (int j = 0; j < 4; ++j) {
            int col = bn + wc * 64 + j * 16 + n16;
            float bv = bias ? bias[col] : 0.0f;
            #pragma unroll
            for (int r = 0; r < 4; ++r) {
                int row = bm + wr * 64 + i * 16 + quad * 4 + r;   // C/D: col=lane&15, row=quad*4+reg
                store_c(&C[(size_t)row * N + col], acc[i][j][r] + bv);
            }
        }
    }
}

// ---------------- RoPE + relayout ----------------
// qkv[t][4608] -> q[h][t][d]  (row-major), kfrag/vfrag frag-major (round-3 verified).
// 256-thread blocks (4 waves, one t each): 4x fewer workgroups than the 64-thread form.
__global__ __launch_bounds__(256) void rope_reorg_kernel(const __hip_bfloat16* __restrict__ qkv,
                                                         const int* __restrict__ positions,
                                                         __hip_bfloat16* __restrict__ qo,
                                                         __hip_bfloat16* __restrict__ ko,
                                                         __hip_bfloat16* __restrict__ vTo) {
    const int t = blockIdx.x * 4 + (threadIdx.x >> 6);
    const int u = blockIdx.y;       // 0..31 q heads, 32..33 k groups, 34..35 v groups
    const int tid = threadIdx.x & 63;   // lane within the wave handling this t
    const int d0 = tid * 2, d1 = d0 + 1;
    int col;
    if (u < 32) col = u * HEAD_DIM;
    else if (u < 34) col = Q_SZ + (u - 32) * HEAD_DIM;
    else col = Q_SZ + KV_SZ + (u - 34) * HEAD_DIM;
    float x0 = __bfloat162float(qkv[(size_t)t * QKV_DIM + col + d0]);
    float x1 = __bfloat162float(qkv[(size_t)t * QKV_DIM + col + d1]);
    float o0 = x0, o1 = x1;
    if (u < 34 && tid < 32) {  // rot_dim = 64: pairs i=0..31; dims 64..127 pass through
        float pos = (float)positions[t];
        float theta = exp2f(-(float)tid * 0.4152410118609203f);  // 10000^(-i/32)
        float ang = pos * theta;
        float sn, cs;
        sincosf(ang, &sn, &cs);
        o0 = x0 * cs - x1 * sn;
        o1 = x1 * cs + x0 * sn;
    }
    if (u < 32) {
        constexpr float qscale = 0.08838834764831845f * 1.4426950408889634f;  // rsqrt(128)*log2e
        __hip_bfloat16* dst = qo + ((size_t)u * T_SEQ + t) * HEAD_DIM;
        dst[d0] = __float2bfloat16(o0 * qscale);
        dst[d1] = __float2bfloat16(o1 * qscale);
    } else if (u < 34) {
        // K frag-major. key t: kt=t>>5, kw=t&31 -> c=(kw>>2)&1, n16=((kw>>3)<<2)|(kw&3)
        const int gg = u - 32;
        const int kt = t >> 5, kw = t & 31;
        const int c = (kw >> 2) & 1;
        const int n16k = ((kw >> 3) << 2) | (kw & 3);
        const int f = d0 >> 5, quad = (d0 >> 3) & 3, j0 = d0 & 7;
        __hip_bfloat16* dst = ko + (size_t)gg * (T_SEQ * HEAD_DIM) +
                              ((size_t)(((kt * 2 + c) * 4 + f)) << 9) + (quad * 16 + n16k) * 8 + j0;
        dst[0] = __float2bfloat16(o0);
        dst[1] = __float2bfloat16(o1);
    } else {
        // V frag-major. key t: kt=t>>5, kw=t&31 -> quad=kw>>3, j=kw&7
        const int gg = u - 34;
        const int kt = t >> 5, kw = t & 31;
        const int quad = kw >> 3, j = kw & 7;
        const int dt0 = d0 >> 4, n0 = d0 & 15;
        __hip_bfloat16* dst = vTo + (size_t)gg * (T_SEQ * HEAD_DIM) +
                              ((size_t)(kt * 8 + dt0) << 9) + (quad * 16 + n0) * 8 + j;
        dst[0] = __float2bfloat16(o0);
        dst[8] = __float2bfloat16(o1);
    }
}

// ---------------- causal GQA flash attention (frag-major K/V, split-K balanced) ----------------
// S^T = K*Q^T with key-row permutation so S C-regs concatenate into the PV B-frag.
// Frag-major K/V (round 3, verified): each kf/vf load reads 64 lanes x 16B = 1KB
// contiguous; flash dropped 251.6 -> ~96 µs.
// Split-K (flash-decoding): chunk pair (p,127-p) split across two waves by key range,
// merged in-block via LDS online-softmax algebra; every wave ~32-33 tiles, exact
// balance, no dispatch-mapping assumptions. No min-waves launch bound (round-1 spill).
__global__ __launch_bounds__(256) void flash_attn_kernel(const __hip_bfloat16* __restrict__ q,
                                                         const __hip_bfloat16* __restrict__ k,
                                                         const __hip_bfloat16* __restrict__ vT,
                                                         __hip_bfloat16* __restrict__ ctx) {
    const int h = blockIdx.y;           // 0..31
    const int g = h >> 4;               // kv group
    const int wave = threadIdx.x >> 6;
    const int lane = threadIdx.x & 63;
    const int n16 = lane & 15, quad = lane >> 4;
    const int wid = blockIdx.x * 4 + wave;   // 0..127
    const int pr = wid >> 1;                 // pair id 0..63
    const int half = wid & 1;                // 0 = early keys, 1 = late keys (incl. diagonal)
    const int pslot = wave >> 1;             // pair slot within block: 0..1
    const __hip_bfloat16* kbase = k + (size_t)g * (T_SEQ * HEAD_DIM) + (size_t)lane * 8;
    const __hip_bfloat16* vbase = vT + (size_t)g * (T_SEQ * HEAD_DIM) + (size_t)lane * 8;

    // merge buffers: stride 33 floats -> bank = (lane + j) % 32, conflict-free
    __shared__ float smO[2][64][33];
    __shared__ float smML[2][64][2];

    for (int pass = 0; pass < 2; ++pass) {
        const int chunk = pass ? (127 - pr) : pr;    // paired light+heavy: 65-66 tiles/pair
        const int qrow0 = chunk * 16;
        const int nt = (chunk >> 1) + 1;             // key tiles for this chunk
        const int ktA = half ? (nt >> 1) : 0;        // this wave's [ktA, ktB) tile range
        const int ktB = half ? nt : (nt >> 1);
        const int qg = qrow0 + n16;

        // Q B-frags: B[n=q(n16)][k=d(quad*8+j)], 4 frags over d=128
        const __hip_bfloat16* qrow = q + ((size_t)h * T_SEQ + qg) * HEAD_DIM;
        bf16x8_t qf[4];
        #pragma unroll
        for (int f = 0; f < 4; ++f)
            qf[f] = *reinterpret_cast<const bf16x8_t*>(qrow + f * 32 + quad * 8);

        f32x4_t accO[8] = {};
        float m_ = -1e30f, l_ = 0.0f;

        if (ktA < ktB) {
            bf16x8_t kf[2][4];
            #pragma unroll
            for (int c = 0; c < 2; ++c)
                #pragma unroll
                for (int f = 0; f < 4; ++f)
                    kf[c][f] = *reinterpret_cast<const bf16x8_t*>(
                        kbase + ((size_t)((ktA * 2 + c) * 4 + f) << 9));

            for (int kt = ktA; kt < ktB; ++kt) {
                // QK^T (transposed): s[c] rows = keys quad*8+c*4+r, cols = q
                f32x4_t s[2] = {};
                #pragma unroll
                for (int c = 0; c < 2; ++c)
                    #pragma unroll
                    for (int f = 0; f < 4; ++f)
                        s[c] = __builtin_amdgcn_mfma_f32_16x16x32_bf16(kf[c][f], qf[f], s[c], 0, 0, 0);
                // prefetch next K tile (WAR on kf orders these after the MFMAs)
                if (kt + 1 < ktB) {
                    int ktn = kt + 1;
                    #pragma unroll
                    for (int c = 0; c < 2; ++c)
                        #pragma unroll
                        for (int f = 0; f < 4; ++f)
                            kf[c][f] = *reinterpret_cast<const bf16x8_t*>(
                                kbase + ((size_t)((ktn * 2 + c) * 4 + f) << 9));
                }
                // V A-frags: A[m=d(n16)][k=key(quad*8+j)] — issued early, consumed after softmax
                bf16x8_t vf[8];
                #pragma unroll
                for (int dt = 0; dt < 8; ++dt)
                    vf[dt] = *reinterpret_cast<const bf16x8_t*>(
                        vbase + ((size_t)(kt * 8 + dt) << 9));

                // causal mask (only tiles crossing the diagonal)
                if (kt * 32 + 31 > qrow0) {
                    #pragma unroll
                    for (int c = 0; c < 2; ++c)
                        #pragma unroll
                        for (int r = 0; r < 4; ++r)
                            if (kt * 32 + quad * 8 + c * 4 + r > qg) s[c][r] = -1e30f;
                }
                // per-lane max over this lane's 8 keys, then 2 shuffles across quads
                float xm = fmaxf(fmaxf(fmaxf(s[0][0], s[0][1]), fmaxf(s[0][2], s[0][3])),
                                 fmaxf(fmaxf(s[1][0], s[1][1]), fmaxf(s[1][2], s[1][3])));
                xm = fmaxf(xm, __shfl_xor(xm, 16, 64));
                xm = fmaxf(xm, __shfl_xor(xm, 32, 64));
                float mn = fmaxf(m_, xm);
                float alpha = __builtin_amdgcn_exp2f(m_ - mn);
                m_ = mn;
                float p[2][4];
                #pragma unroll
                for (int c = 0; c < 2; ++c)
                    #pragma unroll
                    for (int r = 0; r < 4; ++r)
                        p[c][r] = __builtin_amdgcn_exp2f(s[c][r] - mn);
                // pack P^T into the K=32 B-frag: j=0..3 -> tile0, j=4..7 -> tile1
                union { bf16x8_t v; __hip_bfloat16 e[8]; } pf;
                #pragma unroll
                for (int c = 0; c < 2; ++c)
                    #pragma unroll
                    for (int r = 0; r < 4; ++r)
                        pf.e[c * 4 + r] = __float2bfloat16(p[c][r]);
                // rescale O^T by per-lane scalar alpha (skip when no lane's max moved)
                if (__any(alpha < 1.0f)) {
                    #pragma unroll
                    for (int dt = 0; dt < 8; ++dt)
                        #pragma unroll
                        for (int r = 0; r < 4; ++r) accO[dt][r] *= alpha;
                }
                // PV: O^T[d][q] += V^T[d][key] * P^T[key][q]
                #pragma unroll
                for (int dt = 0; dt < 8; ++dt)
                    accO[dt] = __builtin_amdgcn_mfma_f32_16x16x32_bf16(vf[dt], pf.v, accO[dt], 0, 0, 0);
                // l update (independent of PV; scheduler overlaps)
                float xs = ((p[0][0] + p[0][1]) + (p[0][2] + p[0][3])) +
                           ((p[1][0] + p[1][1]) + (p[1][2] + p[1][3]));
                xs += __shfl_xor(xs, 16, 64);
                xs += __shfl_xor(xs, 32, 64);
                l_ = l_ * alpha + xs;
            }
        }

        // ---- merge the two key-halves of this pair through LDS ----
        if (half) {
            #pragma unroll
            for (int dt = 0; dt < 8; ++dt)
                #pragma unroll
                for (int r = 0; r < 4; ++r) smO[pslot][lane][dt * 4 + r] = accO[dt][r];
            smML[pslot][lane][0] = m_;
            smML[pslot][lane][1] = l_;
        }
        __syncthreads();
        if (!half) {
            // half=1 always has >=1 tile (it owns the diagonal) -> mB finite, lB > 0.
            // half=0 may be empty (nt==1): m_=-1e30 -> aA underflows to exactly 0.
            float mB = smML[pslot][lane][0], lB = smML[pslot][lane][1];
            float mN = fmaxf(m_, mB);
            float aA = __builtin_amdgcn_exp2f(m_ - mN);
            float aB = __builtin_amdgcn_exp2f(mB - mN);
            float inv = 1.0f / (l_ * aA + lB * aB);
            #pragma unroll
            for (int dt = 0; dt < 8; ++dt) {
                alignas(8) __hip_bfloat16 o[4];
                #pragma unroll
                for (int r = 0; r < 4; ++r)
                    o[r] = __float2bfloat16((accO[dt][r] * aA + smO[pslot][lane][dt * 4 + r] * aB) * inv);
                // O^T[d][q]: lane writes 4 consecutive d at row t=qg
                *reinterpret_cast<ushort4*>(&ctx[(size_t)qg * Q_SZ + h * HEAD_DIM + dt * 16 + quad * 4]) =
                    *reinterpret_cast<const ushort4*>(o);
            }
        }
        __syncthreads();   // smO/smML reused next pass
    }
}

extern "C" void kernel_launch(void* const* d_in, const int* in_sizes, int n_in,
                              void* d_out, int out_size, void* d_ws, size_t ws_size,
                              hipStream_t stream) {
    (void)in_sizes; (void)n_in; (void)out_size; (void)ws_size;
    const int*   positions = (const int*)d_in[0];
    const float* hidden    = (const float*)d_in[1];
    const float* w_qkv     = (const float*)d_in[2];
    const float* b_qkv     = (const float*)d_in[3];
    const float* w_dense   = (const float*)d_in[4];
    float* out = (float*)d_out;

    char* ws = (char*)d_ws;
    __hip_bfloat16* h_bf   = (__hip_bfloat16*)ws; ws += (size_t)T_SEQ * HIDDEN_SZ * 2;
    __hip_bfloat16* wqkvT  = (__hip_bfloat16*)ws; ws += (size_t)QKV_DIM * HIDDEN_SZ * 2;
    __hip_bfloat16* wdT    = (__hip_bfloat16*)ws; ws += (size_t)HIDDEN_SZ * HIDDEN_SZ * 2;
    __hip_bfloat16* qkv_bf = (__hip_bfloat16*)ws; ws += (size_t)T_SEQ * QKV_DIM * 2;
    __hip_bfloat16* q_bf   = (__hip_bfloat16*)ws; ws += (size_t)NUM_HEADS * T_SEQ * HEAD_DIM * 2;
    __hip_bfloat16* k_bf   = (__hip_bfloat16*)ws; ws += (size_t)KV_GROUPS * T_SEQ * HEAD_DIM * 2;
    __hip_bfloat16* vT_bf  = (__hip_bfloat16*)ws; ws += (size_t)KV_GROUPS * HEAD_DIM * T_SEQ * 2;
    __hip_bfloat16* ctx_bf = h_bf;  // h_bf dead after QKV GEMM; reuse for ctx

    // 1) hidden fp32 -> bf16
    convert_bf16_kernel<<<(T_SEQ * HIDDEN_SZ) / (256 * 4), 256, 0, stream>>>(hidden, h_bf, T_SEQ * HIDDEN_SZ);
    // 2) weights fp32 [K][N] -> bf16 [N][K]
    transpose_convert_kernel<<<dim3(QKV_DIM / 64, HIDDEN_SZ / 64), 256, 0, stream>>>(w_qkv, wqkvT, HIDDEN_SZ, QKV_DIM);
    transpose_convert_kernel<<<dim3(HIDDEN_SZ / 64, HIDDEN_SZ / 64), 256, 0, stream>>>(w_dense, wdT, HIDDEN_SZ, HIDDEN_SZ);
    // 3) QKV GEMM (+bias) -> bf16 qkv   (grid 18*16=288 blocks, %8==0 for XCD swizzle)
    gemm_bf16_kernel<__hip_bfloat16><<<dim3(QKV_DIM / 256, T_SEQ / 128), 512, 0, stream>>>(
        h_bf, wqkvT, b_qkv, qkv_bf, T_SEQ, QKV_DIM, HIDDEN_SZ);
    // 4) RoPE + relayout: Q row-major (pre-scaled), K/V frag-major for coalesced flash loads
    rope_reorg_kernel<<<dim3(T_SEQ / 4, NUM_HEADS + 2 * KV_GROUPS), 256, 0, stream>>>(
        qkv_bf, positions, q_bf, k_bf, vT_bf);
    // 5) causal GQA flash attention (split-K, frag-major K/V) -> ctx bf16 [t][h*128+d]
    flash_attn_kernel<<<dim3(32, NUM_HEADS), 256, 0, stream>>>(q_bf, k_bf, vT_bf, ctx_bf);
    // 6) dense GEMM -> fp32 out   (grid 16*16=256 blocks, %8==0 for XCD swizzle)
    gemm_bf16_kernel<float><<<dim3(HIDDEN_SZ / 256, T_SEQ / 128), 512, 0, stream>>>(
        ctx_bf, wdT, nullptr, out, T_SEQ, HIDDEN_SZ, HIDDEN_SZ);
}